// Round 1
// baseline (1226.270 us; speedup 1.0000x reference)
//
#include <hip/hip_runtime.h>
#include <cstddef>

#define B_SZ   8
#define T_CTX  1024
#define C_DIM  1024
#define H_NUM  16
#define HS     64
#define M_ROWS (B_SZ * T_CTX)

// ---------------------------------------------------------------------------
// SGEMM: C[m,n] = sum_c A'[m,c] * W[n,c] + bias[n], with optional time-shift
// on A (first 512 channels read from row t-1) and per-mode epilogue.
// BM=BN=128, BK=8, 256 threads, 8x8 per thread.
// mode (when shiftA): z=0 -> exp(clip(.,-60,30)) ; z=1 -> identity ; z=2 -> sigmoid
// mode 3 (shiftA==0): multiply by gamma[t]
// ---------------------------------------------------------------------------
__global__ __launch_bounds__(256, 2)
void sgemm_fused(const float* __restrict__ A,
                 const float* __restrict__ W0, const float* __restrict__ W1,
                 const float* __restrict__ W2,
                 const float* __restrict__ b0, const float* __restrict__ b1,
                 const float* __restrict__ b2,
                 float* __restrict__ o0, float* __restrict__ o1, float* __restrict__ o2,
                 const float* __restrict__ gamma, int shiftA)
{
    const int z = blockIdx.z;
    const float* Wm   = (z == 0) ? W0 : (z == 1 ? W1 : W2);
    const float* bias = (z == 0) ? b0 : (z == 1 ? b1 : b2);
    float*       out  = (z == 0) ? o0 : (z == 1 ? o1 : o2);
    const int mode = shiftA ? z : 3;

    __shared__ float As[8][132];
    __shared__ float Bs[8][132];

    const int tid = threadIdx.x;
    const int m0 = blockIdx.y * 128;
    const int n0 = blockIdx.x * 128;
    const int tx = tid & 15;
    const int ty = tid >> 4;

    const int aRow = tid >> 1;        // 0..127
    const int aCol = (tid & 1) * 4;   // 0 or 4

    float acc[8][8];
    #pragma unroll
    for (int i = 0; i < 8; ++i)
        #pragma unroll
        for (int j = 0; j < 8; ++j) acc[i][j] = 0.f;

    for (int k0 = 0; k0 < C_DIM; k0 += 8) {
        // stage loads in registers
        float4 av;
        {
            const int m = m0 + aRow;
            const int c = k0 + aCol;
            if (shiftA && c < 512) {
                const int t = m & (T_CTX - 1);
                if (t == 0) av = make_float4(0.f, 0.f, 0.f, 0.f);
                else        av = *(const float4*)(A + (size_t)(m - 1) * C_DIM + c);
            } else {
                av = *(const float4*)(A + (size_t)m * C_DIM + c);
            }
        }
        const float4 bv = *(const float4*)(Wm + (size_t)(n0 + aRow) * C_DIM + k0 + aCol);

        __syncthreads();   // previous tile fully consumed
        As[aCol + 0][aRow] = av.x;
        As[aCol + 1][aRow] = av.y;
        As[aCol + 2][aRow] = av.z;
        As[aCol + 3][aRow] = av.w;
        Bs[aCol + 0][aRow] = bv.x;
        Bs[aCol + 1][aRow] = bv.y;
        Bs[aCol + 2][aRow] = bv.z;
        Bs[aCol + 3][aRow] = bv.w;
        __syncthreads();

        #pragma unroll
        for (int kk = 0; kk < 8; ++kk) {
            float a[8], b[8];
            *(float4*)&a[0] = *(const float4*)&As[kk][ty * 8];
            *(float4*)&a[4] = *(const float4*)&As[kk][ty * 8 + 4];
            *(float4*)&b[0] = *(const float4*)&Bs[kk][tx * 8];
            *(float4*)&b[4] = *(const float4*)&Bs[kk][tx * 8 + 4];
            #pragma unroll
            for (int i = 0; i < 8; ++i)
                #pragma unroll
                for (int j = 0; j < 8; ++j)
                    acc[i][j] += a[i] * b[j];
        }
    }

    #pragma unroll
    for (int i = 0; i < 8; ++i) {
        const int m = m0 + ty * 8 + i;
        const int t = m & (T_CTX - 1);
        const float g = (mode == 3) ? gamma[t] : 1.f;
        #pragma unroll
        for (int jq = 0; jq < 2; ++jq) {
            const int n = n0 + tx * 8 + jq * 4;
            const float4 bb = *(const float4*)(bias + n);
            float v0 = acc[i][jq * 4 + 0] + bb.x;
            float v1 = acc[i][jq * 4 + 1] + bb.y;
            float v2 = acc[i][jq * 4 + 2] + bb.z;
            float v3 = acc[i][jq * 4 + 3] + bb.w;
            if (mode == 0) {
                v0 = __expf(fminf(fmaxf(v0, -60.f), 30.f));
                v1 = __expf(fminf(fmaxf(v1, -60.f), 30.f));
                v2 = __expf(fminf(fmaxf(v2, -60.f), 30.f));
                v3 = __expf(fminf(fmaxf(v3, -60.f), 30.f));
            } else if (mode == 2) {
                v0 = 1.f / (1.f + __expf(-v0));
                v1 = 1.f / (1.f + __expf(-v1));
                v2 = 1.f / (1.f + __expf(-v2));
                v3 = 1.f / (1.f + __expf(-v3));
            } else if (mode == 3) {
                v0 *= g; v1 *= g; v2 *= g; v3 *= g;
            }
            float4 res = make_float4(v0, v1, v2, v3);
            *(float4*)(out + (size_t)m * C_DIM + n) = res;
        }
    }
}

// ---------------------------------------------------------------------------
// Cumsum of expk over t (chunked, two-level scan) + kv = expk*v in place of v
// ---------------------------------------------------------------------------
__global__ __launch_bounds__(256)
void cumsum_chunk(const float* __restrict__ expk, float* __restrict__ v_kv,
                  float* __restrict__ sumk, float* __restrict__ aux)
{
    const int n = blockIdx.x * 256 + threadIdx.x;   // channel
    const int q = blockIdx.y;                        // t-chunk (128 each)
    const int b = blockIdx.z;
    const size_t base = ((size_t)b * T_CTX + q * 128) * C_DIM + n;
    float s = 0.f;
    #pragma unroll 4
    for (int i = 0; i < 128; ++i) {
        const size_t idx = base + (size_t)i * C_DIM;
        const float e  = expk[idx];
        const float vv = v_kv[idx];
        s += e;
        sumk[idx] = s;
        v_kv[idx] = e * vv;
    }
    aux[((size_t)b * 8 + q) * C_DIM + n] = s;
}

__global__ __launch_bounds__(256)
void scan_aux(float* __restrict__ aux)
{
    const int n = blockIdx.x * 256 + threadIdx.x;
    const int b = blockIdx.z;
    float off = 0.f;
    #pragma unroll
    for (int q = 0; q < 8; ++q) {
        const size_t idx = ((size_t)b * 8 + q) * C_DIM + n;
        const float tmp = aux[idx];
        aux[idx] = off;
        off += tmp;
    }
}

__global__ __launch_bounds__(256)
void add_off(float* __restrict__ sumk, const float* __restrict__ aux)
{
    const int q = blockIdx.y;
    if (q == 0) return;
    const int n = blockIdx.x * 256 + threadIdx.x;
    const int b = blockIdx.z;
    const float off = aux[((size_t)b * 8 + q) * C_DIM + n];
    const size_t base = ((size_t)b * T_CTX + q * 128) * C_DIM + n;
    #pragma unroll 4
    for (int i = 0; i < 128; ++i)
        sumk[base + (size_t)i * C_DIM] += off;
}

// ---------------------------------------------------------------------------
// wkv: per (b,h):  acc[t,c] = sum_{u<=t} tw[h,1023-t+u]*alpha[h,u]*kv[u,c]
// epilogue: rwkv = sigr * beta[h,t] * acc / sumk
// tile: 64 t x 64 c, 256 threads, 4x4 per thread
// ---------------------------------------------------------------------------
__global__ __launch_bounds__(256)
void wkv_kernel(const float* __restrict__ kv, const float* __restrict__ sumk,
                const float* __restrict__ sigr,
                const float* __restrict__ time_w, const float* __restrict__ alpha,
                const float* __restrict__ beta,
                float* __restrict__ rwkv)
{
    __shared__ float tw_s[1024];
    __shared__ float al_s[1024];
    __shared__ float W_s[64][68];
    __shared__ float kv_s[64][68];

    const int tid = threadIdx.x;
    const int t0 = blockIdx.x * 64;
    const int h  = blockIdx.y;
    const int b  = blockIdx.z;

    for (int i = tid; i < 1024; i += 256) {
        tw_s[i] = time_w[h * 1024 + i];
        al_s[i] = alpha[h * 1024 + i];
    }
    __syncthreads();

    const int tx = tid & 15;   // c quads
    const int ty = tid >> 4;   // t quads

    float acc[4][4];
    #pragma unroll
    for (int i = 0; i < 4; ++i)
        #pragma unroll
        for (int j = 0; j < 4; ++j) acc[i][j] = 0.f;

    const size_t baseB = ((size_t)b * T_CTX) * C_DIM + (size_t)h * HS;
    const int i4 = (tid & 15) * 4;
    const int jrow = tid >> 4;

    for (int u0 = 0; u0 <= t0; u0 += 64) {
        __syncthreads();   // previous tile consumed
        // stage kv tile [64u x 64c]
        #pragma unroll
        for (int rep = 0; rep < 4; ++rep) {
            const int r = jrow + rep * 16;
            const float4 val = *(const float4*)(kv + baseB + (size_t)(u0 + r) * C_DIM + i4);
            *(float4*)&kv_s[r][i4] = val;
        }
        // build W tile: W_s[u_rel][t_rel]
        #pragma unroll
        for (int rep = 0; rep < 4; ++rep) {
            const int j = jrow + rep * 16;
            const int u = u0 + j;
            const float a_u = al_s[u];
            #pragma unroll
            for (int ii = 0; ii < 4; ++ii) {
                const int t = t0 + i4 + ii;
                W_s[j][i4 + ii] = (u <= t) ? tw_s[1023 - t + u] * a_u : 0.f;
            }
        }
        __syncthreads();

        #pragma unroll
        for (int uu = 0; uu < 64; ++uu) {
            float4 wv  = *(const float4*)&W_s[uu][ty * 4];
            float4 kvv = *(const float4*)&kv_s[uu][tx * 4];
            const float wa[4] = {wv.x, wv.y, wv.z, wv.w};
            const float kb[4] = {kvv.x, kvv.y, kvv.z, kvv.w};
            #pragma unroll
            for (int i = 0; i < 4; ++i)
                #pragma unroll
                for (int j = 0; j < 4; ++j)
                    acc[i][j] += wa[i] * kb[j];
        }
    }

    // epilogue
    #pragma unroll
    for (int i = 0; i < 4; ++i) {
        const int t = t0 + ty * 4 + i;
        const float bet = beta[h * 1024 + t];
        const size_t row = ((size_t)b * T_CTX + t) * C_DIM + (size_t)h * HS + tx * 4;
        const float4 sr = *(const float4*)(sigr + row);
        const float4 sk = *(const float4*)(sumk + row);
        float4 res;
        res.x = sr.x * bet * acc[i][0] / sk.x;
        res.y = sr.y * bet * acc[i][1] / sk.y;
        res.z = sr.z * bet * acc[i][2] / sk.z;
        res.w = sr.w * bet * acc[i][3] / sk.w;
        *(float4*)(rwkv + row) = res;
    }
}

// ---------------------------------------------------------------------------
extern "C" void kernel_launch(void* const* d_in, const int* in_sizes, int n_in,
                              void* d_out, int out_size, void* d_ws, size_t ws_size,
                              hipStream_t stream)
{
    const float* x     = (const float*)d_in[0];
    const float* tw    = (const float*)d_in[1];
    const float* alpha = (const float*)d_in[2];
    const float* beta  = (const float*)d_in[3];
    const float* gamma = (const float*)d_in[4];
    const float* Wk    = (const float*)d_in[5];
    const float* bk    = (const float*)d_in[6];
    const float* Wv    = (const float*)d_in[7];
    const float* bv    = (const float*)d_in[8];
    const float* Wr    = (const float*)d_in[9];
    const float* br    = (const float*)d_in[10];
    const float* Wo    = (const float*)d_in[11];
    const float* bo    = (const float*)d_in[12];
    float* out = (float*)d_out;

    const size_t NM = (size_t)M_ROWS * C_DIM;   // 8M floats
    float* expk = (float*)d_ws;                 // later reused as rwkv
    float* vkv  = expk + NM;                    // v, overwritten with kv
    float* sigr = vkv + NM;
    float* sumk = sigr + NM;
    float* aux  = sumk + NM;                    // 8*8*1024 floats

    // k,v,r projections (with time shift) + epilogues
    sgemm_fused<<<dim3(8, 64, 3), 256, 0, stream>>>(
        x, Wk, Wv, Wr, bk, bv, br, expk, vkv, sigr, gamma, 1);

    // cumsum(expk) + kv product
    cumsum_chunk<<<dim3(4, 8, 8), 256, 0, stream>>>(expk, vkv, sumk, aux);
    scan_aux<<<dim3(4, 1, 8), 256, 0, stream>>>(aux);
    add_off<<<dim3(4, 8, 8), 256, 0, stream>>>(sumk, aux);

    // causal weighted accumulation + rwkv epilogue (into expk buffer)
    wkv_kernel<<<dim3(16, 16, 8), 256, 0, stream>>>(
        vkv, sumk, sigr, tw, alpha, beta, expk);

    // output projection + gamma
    sgemm_fused<<<dim3(8, 64, 1), 256, 0, stream>>>(
        expk, Wo, nullptr, nullptr, bo, nullptr, nullptr,
        out, nullptr, nullptr, gamma, 0);
}

// Round 2
// 514.825 us; speedup vs baseline: 2.3819x; 2.3819x over previous
//
#include <hip/hip_runtime.h>
#include <hip/hip_bf16.h>
#include <cstddef>
#include <cstdint>

#define B_SZ   8
#define T_CTX  1024
#define C_DIM  1024
#define H_NUM  16
#define HS     64
#define M_ROWS (B_SZ * T_CTX)

typedef __attribute__((ext_vector_type(8))) short bf16x8;
typedef __attribute__((ext_vector_type(4))) float f32x4;

static __device__ inline unsigned short f2bf(float f) {
    __hip_bfloat16 h = __float2bfloat16(f);
    return __builtin_bit_cast(unsigned short, h);
}
static __device__ inline float bf2f(unsigned short u) {
    unsigned int v = ((unsigned int)u) << 16;
    return __builtin_bit_cast(float, v);
}
static __device__ inline void gld16(const void* g, void* l) {
    __builtin_amdgcn_global_load_lds((const __attribute__((address_space(1))) void*)g,
                                     (__attribute__((address_space(3))) void*)l,
                                     16, 0, 0);
}

// ---------------------------------------------------------------------------
// fp32 x -> bf16 xs with time shift (first 512 channels from row t-1)
// ---------------------------------------------------------------------------
__global__ __launch_bounds__(256)
void convert_x(const float* __restrict__ x, unsigned short* __restrict__ xs)
{
    const int idx = (blockIdx.x * 256 + threadIdx.x) * 4;
    const int m = idx >> 10;
    const int c = idx & 1023;
    float4 v;
    if (c < 512) {
        const int t = m & (T_CTX - 1);
        if (t == 0) v = make_float4(0.f, 0.f, 0.f, 0.f);
        else        v = *(const float4*)(x + (size_t)(m - 1) * C_DIM + c);
    } else {
        v = *(const float4*)(x + idx);
    }
    ushort4 o;
    o.x = f2bf(v.x); o.y = f2bf(v.y); o.z = f2bf(v.z); o.w = f2bf(v.w);
    *(ushort4*)(xs + idx) = o;
}

// ---------------------------------------------------------------------------
// fp32 weights -> bf16 (z selects Wk/Wv/Wr/Wo)
// ---------------------------------------------------------------------------
__global__ __launch_bounds__(256)
void convert_w(const float* __restrict__ Wk, const float* __restrict__ Wv,
               const float* __restrict__ Wr, const float* __restrict__ Wo,
               unsigned short* __restrict__ dst)
{
    const int z = blockIdx.z;
    const float* src = (z == 0) ? Wk : (z == 1) ? Wv : (z == 2) ? Wr : Wo;
    const int idx = (blockIdx.x * 256 + threadIdx.x) * 4;
    const float4 v = *(const float4*)(src + idx);
    ushort4 o;
    o.x = f2bf(v.x); o.y = f2bf(v.y); o.z = f2bf(v.z); o.w = f2bf(v.w);
    *(ushort4*)(dst + (size_t)z * (C_DIM * C_DIM) + idx) = o;
}

// ---------------------------------------------------------------------------
// bf16 MFMA GEMM: C[m,n] = sum_k A[m,k]*W[n,k] + bias[n], epilogue by mode.
// 128x128 tile, BK=32, 256 threads (4 waves, 2x2), 16x16x32 MFMA, 4x4 frags.
// mode 0: exp(clip) -> fp32 ; 1: identity -> fp32 ; 2: sigmoid -> bf16 ;
// mode 3: (v+bias)*gamma[t] -> fp32
// ---------------------------------------------------------------------------
__global__ __launch_bounds__(256, 2)
void mfma_gemm(const unsigned short* __restrict__ A,
               const unsigned short* __restrict__ W0,
               const unsigned short* __restrict__ W1,
               const unsigned short* __restrict__ W2,
               const float* __restrict__ b0, const float* __restrict__ b1,
               const float* __restrict__ b2,
               void* __restrict__ o0, void* __restrict__ o1, void* __restrict__ o2,
               const float* __restrict__ gamma, int multi)
{
    const int z    = multi ? blockIdx.z : 0;
    const int mode = multi ? z : 3;
    const unsigned short* Wm = (z == 0) ? W0 : (z == 1) ? W1 : W2;
    const float* bias        = (z == 0) ? b0 : (z == 1) ? b1 : b2;
    void* out                = (z == 0) ? o0 : (z == 1) ? o1 : o2;

    __shared__ unsigned short As[128 * 32];
    __shared__ unsigned short Bs[128 * 32];

    const int tid = threadIdx.x;
    const int w = tid >> 6, l = tid & 63;
    const int m0 = blockIdx.y * 128, n0 = blockIdx.x * 128;

    // staging: each lane moves 16B; wave covers 16 rows/pass, 2 passes each
    const int srow = w * 16 + (l >> 2);
    const int skof = (l & 3) * 8;
    const unsigned short* gA0 = A  + (size_t)(m0 + srow)      * C_DIM + skof;
    const unsigned short* gA1 = A  + (size_t)(m0 + 64 + srow) * C_DIM + skof;
    const unsigned short* gB0 = Wm + (size_t)(n0 + srow)      * C_DIM + skof;
    const unsigned short* gB1 = Wm + (size_t)(n0 + 64 + srow) * C_DIM + skof;
    char* lA0 = (char*)As + (w * 16) * 64;
    char* lA1 = (char*)As + (64 + w * 16) * 64;
    char* lB0 = (char*)Bs + (w * 16) * 64;
    char* lB1 = (char*)Bs + (64 + w * 16) * 64;

    const int wr = w >> 1, wc = w & 1;
    const int lr = l & 15;
    const int lkq = l >> 4;   // k-quad: frag k-offset = lkq*8 elems

    f32x4 acc[4][4];
    #pragma unroll
    for (int i = 0; i < 4; ++i)
        #pragma unroll
        for (int j = 0; j < 4; ++j) acc[i][j] = (f32x4){0.f, 0.f, 0.f, 0.f};

    for (int k0 = 0; k0 < C_DIM; k0 += 32) {
        gld16(gA0 + k0, lA0);
        gld16(gA1 + k0, lA1);
        gld16(gB0 + k0, lB0);
        gld16(gB1 + k0, lB1);
        __syncthreads();

        bf16x8 af[4], bfr[4];
        #pragma unroll
        for (int i = 0; i < 4; ++i)
            af[i] = *(const bf16x8*)&As[(wr * 64 + i * 16 + lr) * 32 + lkq * 8];
        #pragma unroll
        for (int j = 0; j < 4; ++j)
            bfr[j] = *(const bf16x8*)&Bs[(wc * 64 + j * 16 + lr) * 32 + lkq * 8];
        #pragma unroll
        for (int i = 0; i < 4; ++i)
            #pragma unroll
            for (int j = 0; j < 4; ++j)
                acc[i][j] = __builtin_amdgcn_mfma_f32_16x16x32_bf16(
                    af[i], bfr[j], acc[i][j], 0, 0, 0);
        __syncthreads();
    }

    // epilogue: C/D layout col=lane&15, row=(lane>>4)*4+reg
    #pragma unroll
    for (int j = 0; j < 4; ++j) {
        const int col = n0 + wc * 64 + j * 16 + lr;
        const float bz = bias[col];
        #pragma unroll
        for (int i = 0; i < 4; ++i) {
            const int rb = m0 + wr * 64 + i * 16 + lkq * 4;
            #pragma unroll
            for (int r = 0; r < 4; ++r) {
                const int row = rb + r;
                float v = acc[i][j][r] + bz;
                if (mode == 0)      v = __expf(fminf(fmaxf(v, -60.f), 30.f));
                else if (mode == 2) v = 1.f / (1.f + __expf(-v));
                else if (mode == 3) v *= gamma[row & (T_CTX - 1)];
                if (mode == 2)
                    ((unsigned short*)out)[(size_t)row * C_DIM + col] = f2bf(v);
                else
                    ((float*)out)[(size_t)row * C_DIM + col] = v;
            }
        }
    }
}

// ---------------------------------------------------------------------------
// Cumsum of expk over t (chunked, two-level scan) + kv = expk*v in place of v
// ---------------------------------------------------------------------------
__global__ __launch_bounds__(256)
void cumsum_chunk(const float* __restrict__ expk, float* __restrict__ v_kv,
                  float* __restrict__ sumk, float* __restrict__ aux)
{
    const int n = blockIdx.x * 256 + threadIdx.x;
    const int q = blockIdx.y;
    const int b = blockIdx.z;
    const size_t base = ((size_t)b * T_CTX + q * 128) * C_DIM + n;
    float s = 0.f;
    #pragma unroll 4
    for (int i = 0; i < 128; ++i) {
        const size_t idx = base + (size_t)i * C_DIM;
        const float e  = expk[idx];
        const float vv = v_kv[idx];
        s += e;
        sumk[idx] = s;
        v_kv[idx] = e * vv;
    }
    aux[((size_t)b * 8 + q) * C_DIM + n] = s;
}

__global__ __launch_bounds__(256)
void scan_aux(float* __restrict__ aux)
{
    const int n = blockIdx.x * 256 + threadIdx.x;
    const int b = blockIdx.z;
    float off = 0.f;
    #pragma unroll
    for (int q = 0; q < 8; ++q) {
        const size_t idx = ((size_t)b * 8 + q) * C_DIM + n;
        const float tmp = aux[idx];
        aux[idx] = off;
        off += tmp;
    }
}

__global__ __launch_bounds__(256)
void add_off(float* __restrict__ sumk, const float* __restrict__ aux)
{
    const int q = blockIdx.y;
    if (q == 0) return;
    const int n = blockIdx.x * 256 + threadIdx.x;
    const int b = blockIdx.z;
    const float off = aux[((size_t)b * 8 + q) * C_DIM + n];
    const size_t base = ((size_t)b * T_CTX + q * 128) * C_DIM + n;
    #pragma unroll 4
    for (int i = 0; i < 128; ++i)
        sumk[base + (size_t)i * C_DIM] += off;
}

// ---------------------------------------------------------------------------
// wkv: per (b,h):  acc[t,c] = sum_{u<=t} tw[h,1023-t+u]*alpha[h,u]*kv[u,c]
// epilogue: rwkv = sigr * beta[h,t] * acc / sumk  (rwkv written as bf16)
// ---------------------------------------------------------------------------
__global__ __launch_bounds__(256)
void wkv_kernel(const float* __restrict__ kv, const float* __restrict__ sumk,
                const unsigned short* __restrict__ sigr,
                const float* __restrict__ time_w, const float* __restrict__ alpha,
                const float* __restrict__ beta,
                unsigned short* __restrict__ rwkv)
{
    __shared__ float tw_s[1024];
    __shared__ float al_s[1024];
    __shared__ float W_s[64][68];
    __shared__ float kv_s[64][68];

    const int tid = threadIdx.x;
    const int t0 = blockIdx.x * 64;
    const int h  = blockIdx.y;
    const int b  = blockIdx.z;

    for (int i = tid; i < 1024; i += 256) {
        tw_s[i] = time_w[h * 1024 + i];
        al_s[i] = alpha[h * 1024 + i];
    }
    __syncthreads();

    const int tx = tid & 15;
    const int ty = tid >> 4;

    float acc[4][4];
    #pragma unroll
    for (int i = 0; i < 4; ++i)
        #pragma unroll
        for (int j = 0; j < 4; ++j) acc[i][j] = 0.f;

    const size_t baseB = ((size_t)b * T_CTX) * C_DIM + (size_t)h * HS;
    const int i4 = (tid & 15) * 4;
    const int jrow = tid >> 4;

    for (int u0 = 0; u0 <= t0; u0 += 64) {
        __syncthreads();
        #pragma unroll
        for (int rep = 0; rep < 4; ++rep) {
            const int r = jrow + rep * 16;
            const float4 val = *(const float4*)(kv + baseB + (size_t)(u0 + r) * C_DIM + i4);
            *(float4*)&kv_s[r][i4] = val;
        }
        #pragma unroll
        for (int rep = 0; rep < 4; ++rep) {
            const int j = jrow + rep * 16;
            const int u = u0 + j;
            const float a_u = al_s[u];
            #pragma unroll
            for (int ii = 0; ii < 4; ++ii) {
                const int t = t0 + i4 + ii;
                W_s[j][i4 + ii] = (u <= t) ? tw_s[1023 - t + u] * a_u : 0.f;
            }
        }
        __syncthreads();

        #pragma unroll
        for (int uu = 0; uu < 64; ++uu) {
            float4 wv  = *(const float4*)&W_s[uu][ty * 4];
            float4 kvv = *(const float4*)&kv_s[uu][tx * 4];
            const float wa[4] = {wv.x, wv.y, wv.z, wv.w};
            const float kb[4] = {kvv.x, kvv.y, kvv.z, kvv.w};
            #pragma unroll
            for (int i = 0; i < 4; ++i)
                #pragma unroll
                for (int j = 0; j < 4; ++j)
                    acc[i][j] += wa[i] * kb[j];
        }
    }

    #pragma unroll
    for (int i = 0; i < 4; ++i) {
        const int t = t0 + ty * 4 + i;
        const float bet = beta[h * 1024 + t];
        const size_t row = ((size_t)b * T_CTX + t) * C_DIM + (size_t)h * HS + tx * 4;
        const ushort4 sru = *(const ushort4*)(sigr + row);
        const float4 sk = *(const float4*)(sumk + row);
        ushort4 res;
        res.x = f2bf(bf2f(sru.x) * bet * acc[i][0] / sk.x);
        res.y = f2bf(bf2f(sru.y) * bet * acc[i][1] / sk.y);
        res.z = f2bf(bf2f(sru.z) * bet * acc[i][2] / sk.z);
        res.w = f2bf(bf2f(sru.w) * bet * acc[i][3] / sk.w);
        *(ushort4*)(rwkv + row) = res;
    }
}

// ---------------------------------------------------------------------------
extern "C" void kernel_launch(void* const* d_in, const int* in_sizes, int n_in,
                              void* d_out, int out_size, void* d_ws, size_t ws_size,
                              hipStream_t stream)
{
    const float* x     = (const float*)d_in[0];
    const float* tw    = (const float*)d_in[1];
    const float* alpha = (const float*)d_in[2];
    const float* beta  = (const float*)d_in[3];
    const float* gamma = (const float*)d_in[4];
    const float* Wk    = (const float*)d_in[5];
    const float* bk    = (const float*)d_in[6];
    const float* Wv    = (const float*)d_in[7];
    const float* bv    = (const float*)d_in[8];
    const float* Wr    = (const float*)d_in[9];
    const float* br    = (const float*)d_in[10];
    const float* Wo    = (const float*)d_in[11];
    const float* bo    = (const float*)d_in[12];
    float* out = (float*)d_out;

    // workspace layout (bytes):
    //   [0,32M)    expk fp32       (later overlaid by rwkv bf16 [0,16M))
    //   [32M,64M)  vkv fp32
    //   [64M,96M)  sumk fp32       (xs bf16 overlays [64M,80M) -- dead before sumk)
    //   [96M,112M) sigr bf16
    //   [112M,120M) weights bf16 (Wk,Wv,Wr,Wo @ 2MB each)
    //   [120M,+256K) aux fp32
    char* W = (char*)d_ws;
    float* expk          = (float*)W;
    float* vkv           = (float*)(W + (32ull << 20));
    float* sumk          = (float*)(W + (64ull << 20));
    unsigned short* xs   = (unsigned short*)(W + (64ull << 20));
    unsigned short* sigr = (unsigned short*)(W + (96ull << 20));
    unsigned short* wbf  = (unsigned short*)(W + (112ull << 20));
    float* aux           = (float*)(W + (120ull << 20));
    unsigned short* rwkv = (unsigned short*)W;

    const size_t WSZ = (size_t)C_DIM * C_DIM;  // 1M elems per weight matrix

    convert_x<<<dim3(M_ROWS * C_DIM / 1024), 256, 0, stream>>>(x, xs);
    convert_w<<<dim3(1024, 1, 4), 256, 0, stream>>>(Wk, Wv, Wr, Wo, wbf);

    // k,v,r projections: bf16 MFMA + fused epilogues
    mfma_gemm<<<dim3(8, 64, 3), 256, 0, stream>>>(
        xs, wbf, wbf + WSZ, wbf + 2 * WSZ, bk, bv, br,
        expk, vkv, sigr, gamma, 1);

    // cumsum(expk) + kv product
    cumsum_chunk<<<dim3(4, 8, 8), 256, 0, stream>>>(expk, vkv, sumk, aux);
    scan_aux<<<dim3(4, 1, 8), 256, 0, stream>>>(aux);
    add_off<<<dim3(4, 8, 8), 256, 0, stream>>>(sumk, aux);

    // causal weighted accumulation + rwkv epilogue (bf16, into expk space)
    wkv_kernel<<<dim3(16, 16, 8), 256, 0, stream>>>(
        vkv, sumk, sigr, tw, alpha, beta, rwkv);

    // output projection + gamma
    mfma_gemm<<<dim3(8, 64, 1), 256, 0, stream>>>(
        rwkv, wbf + 3 * WSZ, nullptr, nullptr, bo, nullptr, nullptr,
        out, nullptr, nullptr, gamma, 0);
}

// Round 3
// 331.971 us; speedup vs baseline: 3.6939x; 1.5508x over previous
//
#include <hip/hip_runtime.h>
#include <hip/hip_bf16.h>
#include <cstddef>
#include <cstdint>

#define B_SZ   8
#define T_CTX  1024
#define C_DIM  1024
#define H_NUM  16
#define HS     64
#define M_ROWS (B_SZ * T_CTX)

typedef __attribute__((ext_vector_type(8))) short bf16x8;
typedef __attribute__((ext_vector_type(8))) unsigned short u16x8;
typedef __attribute__((ext_vector_type(4))) float f32x4;

static __device__ inline unsigned short f2bf(float f) {
    __hip_bfloat16 h = __float2bfloat16(f);
    return __builtin_bit_cast(unsigned short, h);
}
static __device__ inline float bf2f(unsigned short u) {
    unsigned int v = ((unsigned int)u) << 16;
    return __builtin_bit_cast(float, v);
}
static __device__ inline void gld16(const void* g, void* l) {
    __builtin_amdgcn_global_load_lds((const __attribute__((address_space(1))) void*)g,
                                     (__attribute__((address_space(3))) void*)l,
                                     16, 0, 0);
}

// ---------------------------------------------------------------------------
// fp32 x -> bf16 xs with time shift (first 512 channels from row t-1)
// ---------------------------------------------------------------------------
__global__ __launch_bounds__(256)
void convert_x(const float* __restrict__ x, unsigned short* __restrict__ xs)
{
    const int idx = (blockIdx.x * 256 + threadIdx.x) * 4;
    const int m = idx >> 10;
    const int c = idx & 1023;
    float4 v;
    if (c < 512) {
        const int t = m & (T_CTX - 1);
        if (t == 0) v = make_float4(0.f, 0.f, 0.f, 0.f);
        else        v = *(const float4*)(x + (size_t)(m - 1) * C_DIM + c);
    } else {
        v = *(const float4*)(x + idx);
    }
    ushort4 o;
    o.x = f2bf(v.x); o.y = f2bf(v.y); o.z = f2bf(v.z); o.w = f2bf(v.w);
    *(ushort4*)(xs + idx) = o;
}

// ---------------------------------------------------------------------------
// fp32 weights -> bf16 (z selects Wk/Wv/Wr/Wo)
// ---------------------------------------------------------------------------
__global__ __launch_bounds__(256)
void convert_w(const float* __restrict__ Wk, const float* __restrict__ Wv,
               const float* __restrict__ Wr, const float* __restrict__ Wo,
               unsigned short* __restrict__ dst)
{
    const int z = blockIdx.z;
    const float* src = (z == 0) ? Wk : (z == 1) ? Wv : (z == 2) ? Wr : Wo;
    const int idx = (blockIdx.x * 256 + threadIdx.x) * 4;
    const float4 v = *(const float4*)(src + idx);
    ushort4 o;
    o.x = f2bf(v.x); o.y = f2bf(v.y); o.z = f2bf(v.z); o.w = f2bf(v.w);
    *(ushort4*)(dst + (size_t)z * (C_DIM * C_DIM) + idx) = o;
}

// ---------------------------------------------------------------------------
// bf16 MFMA GEMM: C[m,n] = sum_k A[m,k]*W[n,k] + bias[n], epilogue by mode.
// mode 0: exp(clip) -> fp32 ; 1: identity -> bf16 ; 2: sigmoid -> bf16 ;
// mode 3: (v+bias)*gamma[t] -> fp32
// ---------------------------------------------------------------------------
__global__ __launch_bounds__(256, 2)
void mfma_gemm(const unsigned short* __restrict__ A,
               const unsigned short* __restrict__ W0,
               const unsigned short* __restrict__ W1,
               const unsigned short* __restrict__ W2,
               const float* __restrict__ b0, const float* __restrict__ b1,
               const float* __restrict__ b2,
               void* __restrict__ o0, void* __restrict__ o1, void* __restrict__ o2,
               const float* __restrict__ gamma, int multi)
{
    const int z    = multi ? blockIdx.z : 0;
    const int mode = multi ? z : 3;
    const unsigned short* Wm = (z == 0) ? W0 : (z == 1) ? W1 : W2;
    const float* bias        = (z == 0) ? b0 : (z == 1) ? b1 : b2;
    void* out                = (z == 0) ? o0 : (z == 1) ? o1 : o2;

    __shared__ unsigned short As[128 * 32];
    __shared__ unsigned short Bs[128 * 32];

    const int tid = threadIdx.x;
    const int w = tid >> 6, l = tid & 63;
    const int m0 = blockIdx.y * 128, n0 = blockIdx.x * 128;

    const int srow = w * 16 + (l >> 2);
    const int skof = (l & 3) * 8;
    const unsigned short* gA0 = A  + (size_t)(m0 + srow)      * C_DIM + skof;
    const unsigned short* gA1 = A  + (size_t)(m0 + 64 + srow) * C_DIM + skof;
    const unsigned short* gB0 = Wm + (size_t)(n0 + srow)      * C_DIM + skof;
    const unsigned short* gB1 = Wm + (size_t)(n0 + 64 + srow) * C_DIM + skof;
    char* lA0 = (char*)As + (w * 16) * 64;
    char* lA1 = (char*)As + (64 + w * 16) * 64;
    char* lB0 = (char*)Bs + (w * 16) * 64;
    char* lB1 = (char*)Bs + (64 + w * 16) * 64;

    const int wr = w >> 1, wc = w & 1;
    const int lr = l & 15;
    const int lkq = l >> 4;

    f32x4 acc[4][4];
    #pragma unroll
    for (int i = 0; i < 4; ++i)
        #pragma unroll
        for (int j = 0; j < 4; ++j) acc[i][j] = (f32x4){0.f, 0.f, 0.f, 0.f};

    for (int k0 = 0; k0 < C_DIM; k0 += 32) {
        gld16(gA0 + k0, lA0);
        gld16(gA1 + k0, lA1);
        gld16(gB0 + k0, lB0);
        gld16(gB1 + k0, lB1);
        __syncthreads();

        bf16x8 af[4], bfr[4];
        #pragma unroll
        for (int i = 0; i < 4; ++i)
            af[i] = *(const bf16x8*)&As[(wr * 64 + i * 16 + lr) * 32 + lkq * 8];
        #pragma unroll
        for (int j = 0; j < 4; ++j)
            bfr[j] = *(const bf16x8*)&Bs[(wc * 64 + j * 16 + lr) * 32 + lkq * 8];
        #pragma unroll
        for (int i = 0; i < 4; ++i)
            #pragma unroll
            for (int j = 0; j < 4; ++j)
                acc[i][j] = __builtin_amdgcn_mfma_f32_16x16x32_bf16(
                    af[i], bfr[j], acc[i][j], 0, 0, 0);
        __syncthreads();
    }

    #pragma unroll
    for (int j = 0; j < 4; ++j) {
        const int col = n0 + wc * 64 + j * 16 + lr;
        const float bz = bias[col];
        #pragma unroll
        for (int i = 0; i < 4; ++i) {
            const int rb = m0 + wr * 64 + i * 16 + lkq * 4;
            #pragma unroll
            for (int r = 0; r < 4; ++r) {
                const int row = rb + r;
                float v = acc[i][j][r] + bz;
                if (mode == 0)      v = __expf(fminf(fmaxf(v, -60.f), 30.f));
                else if (mode == 2) v = 1.f / (1.f + __expf(-v));
                else if (mode == 3) v *= gamma[row & (T_CTX - 1)];
                if (mode == 1 || mode == 2)
                    ((unsigned short*)out)[(size_t)row * C_DIM + col] = f2bf(v);
                else
                    ((float*)out)[(size_t)row * C_DIM + col] = v;
            }
        }
    }
}

// ---------------------------------------------------------------------------
// Cumsum of expk over t + kvT[b,h,c,u] = bf16(expk * v * alpha[h,u])
// (transposed bf16 kv for the MFMA wkv kernel; v read as bf16)
// ---------------------------------------------------------------------------
__global__ __launch_bounds__(256)
void cumsum_chunk(const float* __restrict__ expk, const unsigned short* __restrict__ vbf,
                  const float* __restrict__ alpha,
                  float* __restrict__ sumk, unsigned short* __restrict__ kvT,
                  float* __restrict__ aux)
{
    const int n = blockIdx.x * 256 + threadIdx.x;   // global channel
    const int q = blockIdx.y;
    const int b = blockIdx.z;
    const int h = n >> 6, c = n & 63;
    const size_t base = ((size_t)b * T_CTX + q * 128) * C_DIM + n;
    unsigned short* kvrow = kvT + (((size_t)b * H_NUM + h) * HS + c) * T_CTX + q * 128;
    float s = 0.f;
    u16x8 buf;
    for (int i = 0; i < 128; ++i) {
        const size_t idx = base + (size_t)i * C_DIM;
        const float e  = expk[idx];
        const float vv = bf2f(vbf[idx]);
        const float a  = alpha[h * T_CTX + q * 128 + i];
        s += e;
        sumk[idx] = s;
        buf[i & 7] = f2bf(e * vv * a);
        if ((i & 7) == 7) *(u16x8*)(kvrow + i - 7) = buf;
    }
    aux[((size_t)b * 8 + q) * C_DIM + n] = s;
}

__global__ __launch_bounds__(256)
void scan_aux(float* __restrict__ aux)
{
    const int n = blockIdx.x * 256 + threadIdx.x;
    const int b = blockIdx.z;
    float off = 0.f;
    #pragma unroll
    for (int q = 0; q < 8; ++q) {
        const size_t idx = ((size_t)b * 8 + q) * C_DIM + n;
        const float tmp = aux[idx];
        aux[idx] = off;
        off += tmp;
    }
}

__global__ __launch_bounds__(256)
void add_off(float* __restrict__ sumk, const float* __restrict__ aux)
{
    const int q = blockIdx.y;
    if (q == 0) return;
    const int n = blockIdx.x * 256 + threadIdx.x;
    const int b = blockIdx.z;
    const float off = aux[((size_t)b * 8 + q) * C_DIM + n];
    const size_t base = ((size_t)b * T_CTX + q * 128) * C_DIM + n;
    #pragma unroll 4
    for (int i = 0; i < 128; ++i)
        sumk[base + (size_t)i * C_DIM] += off;
}

// ---------------------------------------------------------------------------
// wkv via MFMA, exploiting Toeplitz structure of w:
//   wkv[t,c] = sum_u twx[1023 - t + u] * kvT[c,u],  twx[i>1023] = 0 (causal)
// A-fragment = 8 consecutive twx elems -> read from 8 shift-replicas in LDS
// (replica r holds twx[i+r], so any 2B-misaligned 16B window becomes one
// aligned ds_read_b128).  B = kvT tile staged in padded LDS (144B rows).
// Block: 128 t x 64 c per (b,h); 4 waves 2x2 (wr: t-half, wc: c-half).
// Epilogue: rwkv = sigr * beta[t] * acc / sumk  (bf16)
// ---------------------------------------------------------------------------
#define REPL_STRIDE 1176   // elems; 2352B = 147*16, 588 dwords == 12 mod 32 banks
#define REPL_USED   1168

__global__ __launch_bounds__(256)
void wkv_mfma(const unsigned short* __restrict__ kvT,
              const float* __restrict__ sumk,
              const unsigned short* __restrict__ sigr,
              const float* __restrict__ tw, const float* __restrict__ beta,
              unsigned short* __restrict__ rwkv)
{
    __shared__ unsigned short repl[8 * REPL_STRIDE];  // 18816 B
    __shared__ unsigned short kv_s[64 * 72];          // 9216 B (144B rows)
    __shared__ unsigned short tw_s[1024];             // 2048 B

    const int tid = threadIdx.x;
    const int t0 = blockIdx.x * 128;
    const int h  = blockIdx.y;
    const int b  = blockIdx.z;

    // stage tw (bf16)
    {
        const int i = tid * 4;
        const float4 v = *(const float4*)(tw + h * T_CTX + i);
        ushort4 o;
        o.x = f2bf(v.x); o.y = f2bf(v.y); o.z = f2bf(v.z); o.w = f2bf(v.w);
        *(ushort4*)&tw_s[i] = o;
    }
    __syncthreads();

    // build 8 shift replicas of zero-extended twx
    #pragma unroll
    for (int r = 0; r < 8; ++r)
        for (int i = tid; i < REPL_USED; i += 256) {
            const int src = i + r;
            repl[r * REPL_STRIDE + i] = (src < 1024) ? tw_s[src] : (unsigned short)0;
        }
    __syncthreads();

    const int w = tid >> 6, l = tid & 63;
    const int wr = w >> 1, wc = w & 1;
    const int lr = l & 15, lkq = l >> 4;

    // replica addressing: s = S0 + u0 + kk*32 - i*16 ; addr = 2*s + 2350*r
    const int r    = (7 - lr) & 7;
    const int S0   = 1023 - t0 - wr * 64 - lr + lkq * 8;
    const int abase = 2 * S0 + (2 * REPL_STRIDE - 2) * r;
    const char* repl_c = (const char*)repl;

    // kv staging: thread -> (row=c, two 16B chunks of u)
    const int srow = tid >> 2;
    const int ucol = (tid & 3) * 16;
    const unsigned short* gkv = kvT + (((size_t)b * H_NUM + h) * HS + srow) * T_CTX + ucol;
    unsigned short* skv = &kv_s[srow * 72 + ucol];

    f32x4 acc[4][2];
    #pragma unroll
    for (int i = 0; i < 4; ++i) {
        acc[i][0] = (f32x4){0.f, 0.f, 0.f, 0.f};
        acc[i][1] = (f32x4){0.f, 0.f, 0.f, 0.f};
    }

    const int nsteps = t0 / 64 + 2;
    for (int ks = 0; ks < nsteps; ++ks) {
        const int u0 = ks * 64;
        const u16x8 q0 = *(const u16x8*)(gkv + u0);
        const u16x8 q1 = *(const u16x8*)(gkv + u0 + 8);
        __syncthreads();
        *(u16x8*)skv       = q0;
        *(u16x8*)(skv + 8) = q1;
        __syncthreads();

        const int ub = abase + 2 * u0;
        #pragma unroll
        for (int kk = 0; kk < 2; ++kk) {
            bf16x8 af[4], bfv[2];
            #pragma unroll
            for (int i = 0; i < 4; ++i)
                af[i] = *(const bf16x8*)(repl_c + (ub + kk * 64 - i * 32));
            #pragma unroll
            for (int j = 0; j < 2; ++j)
                bfv[j] = *(const bf16x8*)&kv_s[(wc * 32 + j * 16 + lr) * 72 + kk * 32 + lkq * 8];
            #pragma unroll
            for (int i = 0; i < 4; ++i)
                #pragma unroll
                for (int j = 0; j < 2; ++j)
                    acc[i][j] = __builtin_amdgcn_mfma_f32_16x16x32_bf16(
                        af[i], bfv[j], acc[i][j], 0, 0, 0);
        }
    }

    // epilogue
    #pragma unroll
    for (int i = 0; i < 4; ++i) {
        const int tb = t0 + wr * 64 + i * 16 + lkq * 4;
        #pragma unroll
        for (int rg = 0; rg < 4; ++rg) {
            const int t = tb + rg;
            const float bet = beta[h * T_CTX + t];
            const size_t row_off = ((size_t)(b * T_CTX + t)) * C_DIM + h * HS;
            #pragma unroll
            for (int j = 0; j < 2; ++j) {
                const int cl = wc * 32 + j * 16 + lr;
                const float sk = sumk[row_off + cl];
                const float sr = bf2f(sigr[row_off + cl]);
                rwkv[row_off + cl] = f2bf(sr * bet * acc[i][j][rg] / sk);
            }
        }
    }
}

// ---------------------------------------------------------------------------
extern "C" void kernel_launch(void* const* d_in, const int* in_sizes, int n_in,
                              void* d_out, int out_size, void* d_ws, size_t ws_size,
                              hipStream_t stream)
{
    const float* x     = (const float*)d_in[0];
    const float* tw    = (const float*)d_in[1];
    const float* alpha = (const float*)d_in[2];
    const float* beta  = (const float*)d_in[3];
    const float* gamma = (const float*)d_in[4];
    const float* Wk    = (const float*)d_in[5];
    const float* bk    = (const float*)d_in[6];
    const float* Wv    = (const float*)d_in[7];
    const float* bv    = (const float*)d_in[8];
    const float* Wr    = (const float*)d_in[9];
    const float* br    = (const float*)d_in[10];
    const float* Wo    = (const float*)d_in[11];
    const float* bo    = (const float*)d_in[12];
    float* out = (float*)d_out;

    // workspace layout (bytes), max 128M:
    //  [0,32M)   expk fp32    -> rwkv bf16 [0,16M) after cumsum
    //  [32,48M)  v bf16
    //  [48,56M)  weights bf16 (Wk,Wv,Wr,Wo @ 2MB)
    //  [56,56.25M) aux
    //  [64,96M)  sumk fp32    (xs bf16 overlays [64,80M) during projections)
    //  [96,112M) sigr bf16
    //  [112,128M) kvT bf16
    char* W = (char*)d_ws;
    float* expk          = (float*)W;
    unsigned short* rwkv = (unsigned short*)W;
    unsigned short* vbf  = (unsigned short*)(W + (32ull << 20));
    unsigned short* wbf  = (unsigned short*)(W + (48ull << 20));
    float* aux           = (float*)(W + (56ull << 20));
    float* sumk          = (float*)(W + (64ull << 20));
    unsigned short* xs   = (unsigned short*)(W + (64ull << 20));
    unsigned short* sigr = (unsigned short*)(W + (96ull << 20));
    unsigned short* kvT  = (unsigned short*)(W + (112ull << 20));

    const size_t WSZ = (size_t)C_DIM * C_DIM;

    convert_x<<<dim3(M_ROWS * C_DIM / 1024), 256, 0, stream>>>(x, xs);
    convert_w<<<dim3(1024, 1, 4), 256, 0, stream>>>(Wk, Wv, Wr, Wo, wbf);

    mfma_gemm<<<dim3(8, 64, 3), 256, 0, stream>>>(
        xs, wbf, wbf + WSZ, wbf + 2 * WSZ, bk, bv, br,
        expk, vbf, sigr, gamma, 1);

    cumsum_chunk<<<dim3(4, 8, 8), 256, 0, stream>>>(expk, vbf, alpha, sumk, kvT, aux);
    scan_aux<<<dim3(4, 1, 8), 256, 0, stream>>>(aux);
    add_off<<<dim3(4, 8, 8), 256, 0, stream>>>(sumk, aux);

    wkv_mfma<<<dim3(8, 16, 8), 256, 0, stream>>>(
        kvT, sumk, sigr, tw, beta, rwkv);

    mfma_gemm<<<dim3(8, 64, 1), 256, 0, stream>>>(
        rwkv, wbf + 3 * WSZ, nullptr, nullptr, bo, nullptr, nullptr,
        out, nullptr, nullptr, gamma, 0);
}

// Round 4
// 296.235 us; speedup vs baseline: 4.1395x; 1.1206x over previous
//
#include <hip/hip_runtime.h>
#include <hip/hip_bf16.h>
#include <cstddef>
#include <cstdint>

#define B_SZ   8
#define T_CTX  1024
#define C_DIM  1024
#define H_NUM  16
#define HS     64
#define M_ROWS (B_SZ * T_CTX)

typedef __attribute__((ext_vector_type(8))) short bf16x8;
typedef __attribute__((ext_vector_type(8))) unsigned short u16x8;
typedef __attribute__((ext_vector_type(4))) float f32x4;

static __device__ inline unsigned short f2bf(float f) {
    __hip_bfloat16 h = __float2bfloat16(f);
    return __builtin_bit_cast(unsigned short, h);
}
static __device__ inline float bf2f(unsigned short u) {
    unsigned int v = ((unsigned int)u) << 16;
    return __builtin_bit_cast(float, v);
}
static __device__ inline void gld16(const void* g, void* l) {
    __builtin_amdgcn_global_load_lds((const __attribute__((address_space(1))) void*)g,
                                     (__attribute__((address_space(3))) void*)l,
                                     16, 0, 0);
}

// ---------------------------------------------------------------------------
// fp32 x -> bf16 xs with time shift (first 512 channels from row t-1)
// ---------------------------------------------------------------------------
__global__ __launch_bounds__(256)
void convert_x(const float* __restrict__ x, unsigned short* __restrict__ xs)
{
    const int idx = (blockIdx.x * 256 + threadIdx.x) * 4;
    const int m = idx >> 10;
    const int c = idx & 1023;
    float4 v;
    if (c < 512) {
        const int t = m & (T_CTX - 1);
        if (t == 0) v = make_float4(0.f, 0.f, 0.f, 0.f);
        else        v = *(const float4*)(x + (size_t)(m - 1) * C_DIM + c);
    } else {
        v = *(const float4*)(x + idx);
    }
    ushort4 o;
    o.x = f2bf(v.x); o.y = f2bf(v.y); o.z = f2bf(v.z); o.w = f2bf(v.w);
    *(ushort4*)(xs + idx) = o;
}

// ---------------------------------------------------------------------------
// fp32 weights -> bf16 stacked [Wk;Wv;Wr;Wo] (4096 x 1024)
// ---------------------------------------------------------------------------
__global__ __launch_bounds__(256)
void convert_w(const float* __restrict__ Wk, const float* __restrict__ Wv,
               const float* __restrict__ Wr, const float* __restrict__ Wo,
               unsigned short* __restrict__ dst)
{
    const int z = blockIdx.z;
    const float* src = (z == 0) ? Wk : (z == 1) ? Wv : (z == 2) ? Wr : Wo;
    const int idx = (blockIdx.x * 256 + threadIdx.x) * 4;
    const float4 v = *(const float4*)(src + idx);
    ushort4 o;
    o.x = f2bf(v.x); o.y = f2bf(v.y); o.z = f2bf(v.z); o.w = f2bf(v.w);
    *(ushort4*)(dst + (size_t)z * (C_DIM * C_DIM) + idx) = o;
}

// ---------------------------------------------------------------------------
// bf16 MFMA GEMM, BK=64: C[m,n] = sum_k A[m,k]*W[n,k] + bias, fused epilogue.
// multi=1: W stacked [3072x1024] (k,v,r); mode = n0>>10:
//   0: exp(clip)->fp32 expk ; 1: identity->bf16 v ; 2: sigmoid->bf16 sigr
// multi=0: mode 3: (v+bias)*gamma[t] -> fp32 out
// Block swizzle: d -> y=((d&7)<<3)|((d>>3)&7), x=d>>6 so each XCD (d%8) owns
// 8 consecutive M-bands across all N-tiles (A band set = 2MB, L2-resident).
// ---------------------------------------------------------------------------
__global__ __launch_bounds__(256, 2)
void mfma_gemm64(const unsigned short* __restrict__ A,
                 const unsigned short* __restrict__ Wb,
                 const float* __restrict__ b0, const float* __restrict__ b1,
                 const float* __restrict__ b2,
                 void* __restrict__ o0, void* __restrict__ o1, void* __restrict__ o2,
                 const float* __restrict__ gamma, int multi)
{
    const int d  = blockIdx.x;
    const int y  = ((d & 7) << 3) | ((d >> 3) & 7);
    const int xb = d >> 6;
    const int m0 = y * 128, n0 = xb * 128;

    int mode, ncol0;
    const float* bias;
    void* out;
    if (multi) {
        const int z = n0 >> 10;
        mode = z;
        ncol0 = n0 & 1023;
        bias = (z == 0) ? b0 : (z == 1) ? b1 : b2;
        out  = (z == 0) ? o0 : (z == 1) ? o1 : o2;
    } else {
        mode = 3; ncol0 = n0; bias = b0; out = o0;
    }

    __shared__ unsigned short As[128 * 64];
    __shared__ unsigned short Bs[128 * 64];

    const int tid = threadIdx.x;
    const int w = tid >> 6, l = tid & 63;

    // staging: wave w covers rows [w*32, w*32+32) in 4 rounds of 8 rows
    const int r8  = l >> 3;          // row within 8
    const int c16 = (l & 7) * 8;     // elem offset (16B)
    const unsigned short* gA = A  + (size_t)(m0 + w * 32 + r8) * C_DIM + c16;
    const unsigned short* gB = Wb + (size_t)(n0 + w * 32 + r8) * C_DIM + c16;
    char* lA = (char*)As + (w * 32) * 128;
    char* lB = (char*)Bs + (w * 32) * 128;

    const int wr = w >> 1, wc = w & 1;
    const int lr = l & 15, lkq = l >> 4;

    f32x4 acc[4][4];
    #pragma unroll
    for (int i = 0; i < 4; ++i)
        #pragma unroll
        for (int j = 0; j < 4; ++j) acc[i][j] = (f32x4){0.f, 0.f, 0.f, 0.f};

    for (int k0 = 0; k0 < C_DIM; k0 += 64) {
        #pragma unroll
        for (int r = 0; r < 4; ++r) {
            gld16(gA + k0 + (size_t)r * 8 * C_DIM, lA + r * 8 * 128);
            gld16(gB + k0 + (size_t)r * 8 * C_DIM, lB + r * 8 * 128);
        }
        __syncthreads();

        bf16x8 af[2][4], bfv[2][4];
        #pragma unroll
        for (int ks = 0; ks < 2; ++ks) {
            #pragma unroll
            for (int i = 0; i < 4; ++i)
                af[ks][i] = *(const bf16x8*)&As[(wr * 64 + i * 16 + lr) * 64 + ks * 32 + lkq * 8];
            #pragma unroll
            for (int j = 0; j < 4; ++j)
                bfv[ks][j] = *(const bf16x8*)&Bs[(wc * 64 + j * 16 + lr) * 64 + ks * 32 + lkq * 8];
        }
        #pragma unroll
        for (int ks = 0; ks < 2; ++ks)
            #pragma unroll
            for (int i = 0; i < 4; ++i)
                #pragma unroll
                for (int j = 0; j < 4; ++j)
                    acc[i][j] = __builtin_amdgcn_mfma_f32_16x16x32_bf16(
                        af[ks][i], bfv[ks][j], acc[i][j], 0, 0, 0);
        __syncthreads();
    }

    // epilogue: C/D layout col=lane&15, row=(lane>>4)*4+reg
    #pragma unroll
    for (int j = 0; j < 4; ++j) {
        const int col = ncol0 + wc * 64 + j * 16 + lr;
        const float bz = bias[col];
        #pragma unroll
        for (int i = 0; i < 4; ++i) {
            const int rb = m0 + wr * 64 + i * 16 + lkq * 4;
            #pragma unroll
            for (int r = 0; r < 4; ++r) {
                const int row = rb + r;
                float v = acc[i][j][r] + bz;
                if (mode == 0)      v = __expf(fminf(fmaxf(v, -60.f), 30.f));
                else if (mode == 2) v = 1.f / (1.f + __expf(-v));
                else if (mode == 3) v *= gamma[row & (T_CTX - 1)];
                if (mode == 1 || mode == 2)
                    ((unsigned short*)out)[(size_t)row * C_DIM + col] = f2bf(v);
                else
                    ((float*)out)[(size_t)row * C_DIM + col] = v;
            }
        }
    }
}

// ---------------------------------------------------------------------------
// Chunk-local cumsum of expk + kvT[b,h,c,u] = bf16(expk * v * alpha[h,u]).
// sumk holds CHUNK-LOCAL prefix sums; global offset (aux) folded in at the
// wkv epilogue.  aux[b,q,n] = chunk total, exclusive-scanned by scan_aux.
// ---------------------------------------------------------------------------
__global__ __launch_bounds__(256)
void cumsum_chunk(const float* __restrict__ expk, const unsigned short* __restrict__ vbf,
                  const float* __restrict__ alpha,
                  float* __restrict__ sumk, unsigned short* __restrict__ kvT,
                  float* __restrict__ aux)
{
    const int n = blockIdx.x * 256 + threadIdx.x;
    const int q = blockIdx.y;
    const int b = blockIdx.z;
    const int h = n >> 6, c = n & 63;
    const size_t base = ((size_t)b * T_CTX + q * 128) * C_DIM + n;
    unsigned short* kvrow = kvT + (((size_t)b * H_NUM + h) * HS + c) * T_CTX + q * 128;
    float s = 0.f;
    u16x8 buf;
    for (int i = 0; i < 128; ++i) {
        const size_t idx = base + (size_t)i * C_DIM;
        const float e  = expk[idx];
        const float vv = bf2f(vbf[idx]);
        const float a  = alpha[h * T_CTX + q * 128 + i];
        s += e;
        sumk[idx] = s;
        buf[i & 7] = f2bf(e * vv * a);
        if ((i & 7) == 7) *(u16x8*)(kvrow + i - 7) = buf;
    }
    aux[((size_t)b * 8 + q) * C_DIM + n] = s;
}

__global__ __launch_bounds__(256)
void scan_aux(float* __restrict__ aux)
{
    const int n = blockIdx.x * 256 + threadIdx.x;
    const int b = blockIdx.z;
    float off = 0.f;
    #pragma unroll
    for (int q = 0; q < 8; ++q) {
        const size_t idx = ((size_t)b * 8 + q) * C_DIM + n;
        const float tmp = aux[idx];
        aux[idx] = off;
        off += tmp;
    }
}

// ---------------------------------------------------------------------------
// wkv via MFMA (Toeplitz):  wkv[t,c] = sum_u twx[1023-t+u] * kvT[c,u]
// A-frags from 8 shift-replicas of twx in LDS; B = kvT tile in padded LDS.
// Epilogue: rwkv = sigr * beta[t] * acc / (sumk_chunk + aux_offset)  (bf16)
// ---------------------------------------------------------------------------
#define REPL_STRIDE 1176
#define REPL_USED   1168

__global__ __launch_bounds__(256)
void wkv_mfma(const unsigned short* __restrict__ kvT,
              const float* __restrict__ sumk,
              const unsigned short* __restrict__ sigr,
              const float* __restrict__ tw, const float* __restrict__ beta,
              const float* __restrict__ aux,
              unsigned short* __restrict__ rwkv)
{
    __shared__ unsigned short repl[8 * REPL_STRIDE];
    __shared__ unsigned short kv_s[64 * 72];
    __shared__ unsigned short tw_s[1024];

    const int tid = threadIdx.x;
    const int t0 = blockIdx.x * 128;
    const int h  = blockIdx.y;
    const int b  = blockIdx.z;

    {
        const int i = tid * 4;
        const float4 v = *(const float4*)(tw + h * T_CTX + i);
        ushort4 o;
        o.x = f2bf(v.x); o.y = f2bf(v.y); o.z = f2bf(v.z); o.w = f2bf(v.w);
        *(ushort4*)&tw_s[i] = o;
    }
    __syncthreads();

    #pragma unroll
    for (int r = 0; r < 8; ++r)
        for (int i = tid; i < REPL_USED; i += 256) {
            const int src = i + r;
            repl[r * REPL_STRIDE + i] = (src < 1024) ? tw_s[src] : (unsigned short)0;
        }
    __syncthreads();

    const int w = tid >> 6, l = tid & 63;
    const int wr = w >> 1, wc = w & 1;
    const int lr = l & 15, lkq = l >> 4;

    const int r    = (7 - lr) & 7;
    const int S0   = 1023 - t0 - wr * 64 - lr + lkq * 8;
    const int abase = 2 * S0 + (2 * REPL_STRIDE - 2) * r;
    const char* repl_c = (const char*)repl;

    const int srow = tid >> 2;
    const int ucol = (tid & 3) * 16;
    const unsigned short* gkv = kvT + (((size_t)b * H_NUM + h) * HS + srow) * T_CTX + ucol;
    unsigned short* skv = &kv_s[srow * 72 + ucol];

    f32x4 acc[4][2];
    #pragma unroll
    for (int i = 0; i < 4; ++i) {
        acc[i][0] = (f32x4){0.f, 0.f, 0.f, 0.f};
        acc[i][1] = (f32x4){0.f, 0.f, 0.f, 0.f};
    }

    const int nsteps = t0 / 64 + 2;
    for (int ks = 0; ks < nsteps; ++ks) {
        const int u0 = ks * 64;
        const u16x8 q0 = *(const u16x8*)(gkv + u0);
        const u16x8 q1 = *(const u16x8*)(gkv + u0 + 8);
        __syncthreads();
        *(u16x8*)skv       = q0;
        *(u16x8*)(skv + 8) = q1;
        __syncthreads();

        const int ub = abase + 2 * u0;
        #pragma unroll
        for (int kk = 0; kk < 2; ++kk) {
            bf16x8 af[4], bfv[2];
            #pragma unroll
            for (int i = 0; i < 4; ++i)
                af[i] = *(const bf16x8*)(repl_c + (ub + kk * 64 - i * 32));
            #pragma unroll
            for (int j = 0; j < 2; ++j)
                bfv[j] = *(const bf16x8*)&kv_s[(wc * 32 + j * 16 + lr) * 72 + kk * 32 + lkq * 8];
            #pragma unroll
            for (int i = 0; i < 4; ++i)
                #pragma unroll
                for (int j = 0; j < 2; ++j)
                    acc[i][j] = __builtin_amdgcn_mfma_f32_16x16x32_bf16(
                        af[i], bfv[j], acc[i][j], 0, 0, 0);
        }
    }

    #pragma unroll
    for (int i = 0; i < 4; ++i) {
        const int tb = t0 + wr * 64 + i * 16 + lkq * 4;
        #pragma unroll
        for (int rg = 0; rg < 4; ++rg) {
            const int t = tb + rg;
            const int q = t >> 7;
            const float bet = beta[h * T_CTX + t];
            const size_t row_off = ((size_t)(b * T_CTX + t)) * C_DIM + h * HS;
            const size_t aux_off = ((size_t)b * 8 + q) * C_DIM + h * HS;
            #pragma unroll
            for (int j = 0; j < 2; ++j) {
                const int cl = wc * 32 + j * 16 + lr;
                const float sk = sumk[row_off + cl] + aux[aux_off + cl];
                const float sr = bf2f(sigr[row_off + cl]);
                rwkv[row_off + cl] = f2bf(sr * bet * acc[i][j][rg] / sk);
            }
        }
    }
}

// ---------------------------------------------------------------------------
extern "C" void kernel_launch(void* const* d_in, const int* in_sizes, int n_in,
                              void* d_out, int out_size, void* d_ws, size_t ws_size,
                              hipStream_t stream)
{
    const float* x     = (const float*)d_in[0];
    const float* tw    = (const float*)d_in[1];
    const float* alpha = (const float*)d_in[2];
    const float* beta  = (const float*)d_in[3];
    const float* gamma = (const float*)d_in[4];
    const float* Wk    = (const float*)d_in[5];
    const float* bk    = (const float*)d_in[6];
    const float* Wv    = (const float*)d_in[7];
    const float* bv    = (const float*)d_in[8];
    const float* Wr    = (const float*)d_in[9];
    const float* br    = (const float*)d_in[10];
    const float* Wo    = (const float*)d_in[11];
    const float* bo    = (const float*)d_in[12];
    float* out = (float*)d_out;

    // workspace layout (bytes), max 128M:
    //  [0,32M)   expk fp32    -> rwkv bf16 [0,16M) after cumsum
    //  [32,48M)  v bf16
    //  [48,56M)  weights bf16 (Wk,Wv,Wr,Wo stacked @ 2MB each)
    //  [56,56.25M) aux
    //  [64,96M)  sumk fp32 (chunk-local)  (xs bf16 overlays [64,80M) during proj)
    //  [96,112M) sigr bf16
    //  [112,128M) kvT bf16
    char* W = (char*)d_ws;
    float* expk          = (float*)W;
    unsigned short* rwkv = (unsigned short*)W;
    unsigned short* vbf  = (unsigned short*)(W + (32ull << 20));
    unsigned short* wbf  = (unsigned short*)(W + (48ull << 20));
    float* aux           = (float*)(W + (56ull << 20));
    float* sumk          = (float*)(W + (64ull << 20));
    unsigned short* xs   = (unsigned short*)(W + (64ull << 20));
    unsigned short* sigr = (unsigned short*)(W + (96ull << 20));
    unsigned short* kvT  = (unsigned short*)(W + (112ull << 20));

    const size_t WSZ = (size_t)C_DIM * C_DIM;

    convert_x<<<dim3(M_ROWS * C_DIM / 1024), 256, 0, stream>>>(x, xs);
    convert_w<<<dim3(1024, 1, 4), 256, 0, stream>>>(Wk, Wv, Wr, Wo, wbf);

    // k,v,r projections as one N=3072 GEMM (W stacked), XCD-swizzled
    mfma_gemm64<<<dim3(1536), 256, 0, stream>>>(
        xs, wbf, bk, bv, br, expk, vbf, sigr, gamma, 1);

    cumsum_chunk<<<dim3(4, 8, 8), 256, 0, stream>>>(expk, vbf, alpha, sumk, kvT, aux);
    scan_aux<<<dim3(4, 1, 8), 256, 0, stream>>>(aux);

    wkv_mfma<<<dim3(8, 16, 8), 256, 0, stream>>>(
        kvT, sumk, sigr, tw, beta, aux, rwkv);

    // output projection + gamma
    mfma_gemm64<<<dim3(512), 256, 0, stream>>>(
        rwkv, wbf + 3 * WSZ, bo, nullptr, nullptr,
        out, nullptr, nullptr, gamma, 0);
}

// Round 5
// 269.871 us; speedup vs baseline: 4.5439x; 1.0977x over previous
//
#include <hip/hip_runtime.h>
#include <hip/hip_bf16.h>
#include <cstddef>
#include <cstdint>

#define B_SZ   8
#define T_CTX  1024
#define C_DIM  1024
#define H_NUM  16
#define HS     64
#define M_ROWS (B_SZ * T_CTX)

typedef __attribute__((ext_vector_type(8))) short bf16x8;
typedef __attribute__((ext_vector_type(8))) unsigned short u16x8;
typedef __attribute__((ext_vector_type(4))) float f32x4;

static __device__ inline unsigned short f2bf(float f) {
    __hip_bfloat16 h = __float2bfloat16(f);
    return __builtin_bit_cast(unsigned short, h);
}
static __device__ inline float bf2f(unsigned short u) {
    unsigned int v = ((unsigned int)u) << 16;
    return __builtin_bit_cast(float, v);
}
static __device__ inline void gld16(const void* g, void* l) {
    __builtin_amdgcn_global_load_lds((const __attribute__((address_space(1))) void*)g,
                                     (__attribute__((address_space(3))) void*)l,
                                     16, 0, 0);
}

// ---------------------------------------------------------------------------
// Fused conversion: blocks [0,8192) do x->xs (bf16, time-shifted);
// blocks [8192,12288) do the 4 weight matrices -> stacked bf16.
// ---------------------------------------------------------------------------
__global__ __launch_bounds__(256)
void convert_all(const float* __restrict__ x, unsigned short* __restrict__ xs,
                 const float* __restrict__ Wk, const float* __restrict__ Wv,
                 const float* __restrict__ Wr, const float* __restrict__ Wo,
                 unsigned short* __restrict__ wdst)
{
    const int bid = blockIdx.x;
    if (bid < 8192) {
        const int idx = (bid * 256 + threadIdx.x) * 4;
        const int m = idx >> 10;
        const int c = idx & 1023;
        float4 v;
        if (c < 512) {
            const int t = m & (T_CTX - 1);
            if (t == 0) v = make_float4(0.f, 0.f, 0.f, 0.f);
            else        v = *(const float4*)(x + (size_t)(m - 1) * C_DIM + c);
        } else {
            v = *(const float4*)(x + idx);
        }
        ushort4 o;
        o.x = f2bf(v.x); o.y = f2bf(v.y); o.z = f2bf(v.z); o.w = f2bf(v.w);
        *(ushort4*)(xs + idx) = o;
    } else {
        const int wid = bid - 8192;
        const int z = wid >> 10;
        const float* src = (z == 0) ? Wk : (z == 1) ? Wv : (z == 2) ? Wr : Wo;
        const int idx = ((wid & 1023) * 256 + threadIdx.x) * 4;
        const float4 v = *(const float4*)(src + idx);
        ushort4 o;
        o.x = f2bf(v.x); o.y = f2bf(v.y); o.z = f2bf(v.z); o.w = f2bf(v.w);
        *(ushort4*)(wdst + (size_t)z * (C_DIM * C_DIM) + idx) = o;
    }
}

// ---------------------------------------------------------------------------
// bf16 MFMA GEMM, BK=64, XOR-swizzled LDS (slot = chunk ^ (row&7)) to break
// the 16-way bank conflict of 128B-row fragment reads down to the b128
// 8-lane minimum.  Staging keeps gld16-contiguous writes; the lane->global
// chunk mapping carries the permutation.
// multi=1: W stacked [3072x1024]; mode = n0>>10:
//   0: exp(clip)->fp32 expk ; 1: identity->bf16 v ; 2: sigmoid->bf16 sigr
// multi=0: mode 3: (v+bias)*gamma[t] -> fp32 out
// Block swizzle: d -> y=((d&7)<<3)|((d>>3)&7), x=d>>6 (XCD L2 locality).
// ---------------------------------------------------------------------------
__global__ __launch_bounds__(256, 2)
void mfma_gemm64(const unsigned short* __restrict__ A,
                 const unsigned short* __restrict__ Wb,
                 const float* __restrict__ b0, const float* __restrict__ b1,
                 const float* __restrict__ b2,
                 void* __restrict__ o0, void* __restrict__ o1, void* __restrict__ o2,
                 const float* __restrict__ gamma, int multi)
{
    const int d  = blockIdx.x;
    const int y  = ((d & 7) << 3) | ((d >> 3) & 7);
    const int xb = d >> 6;
    const int m0 = y * 128, n0 = xb * 128;

    int mode, ncol0;
    const float* bias;
    void* out;
    if (multi) {
        const int z = n0 >> 10;
        mode = z;
        ncol0 = n0 & 1023;
        bias = (z == 0) ? b0 : (z == 1) ? b1 : b2;
        out  = (z == 0) ? o0 : (z == 1) ? o1 : o2;
    } else {
        mode = 3; ncol0 = n0; bias = b0; out = o0;
    }

    __shared__ unsigned short As[128 * 64];
    __shared__ unsigned short Bs[128 * 64];

    const int tid = threadIdx.x;
    const int w = tid >> 6, l = tid & 63;

    // staging: wave w covers rows [w*32, w*32+32) in 4 rounds of 8 rows.
    // lane l -> row offset r8 = l>>3, fetches global k-chunk (l&7)^r8 so the
    // contiguous LDS write leaves slot s of row R holding chunk s^(R&7).
    const int r8  = l >> 3;
    const int c16 = ((l & 7) ^ r8) * 8;
    const unsigned short* gA = A  + (size_t)(m0 + w * 32 + r8) * C_DIM + c16;
    const unsigned short* gB = Wb + (size_t)(n0 + w * 32 + r8) * C_DIM + c16;
    char* lA = (char*)As + (w * 32) * 128;
    char* lB = (char*)Bs + (w * 32) * 128;

    const int wr = w >> 1, wc = w & 1;
    const int lr = l & 15, lkq = l >> 4;
    const int x7 = lr & 7;

    f32x4 acc[4][4];
    #pragma unroll
    for (int i = 0; i < 4; ++i)
        #pragma unroll
        for (int j = 0; j < 4; ++j) acc[i][j] = (f32x4){0.f, 0.f, 0.f, 0.f};

    for (int k0 = 0; k0 < C_DIM; k0 += 64) {
        #pragma unroll
        for (int r = 0; r < 4; ++r) {
            gld16(gA + k0 + (size_t)r * 8 * C_DIM, lA + r * 8 * 128);
            gld16(gB + k0 + (size_t)r * 8 * C_DIM, lB + r * 8 * 128);
        }
        __syncthreads();

        bf16x8 af[2][4], bfv[2][4];
        #pragma unroll
        for (int ks = 0; ks < 2; ++ks) {
            const int slot = ((ks * 4 + lkq) ^ x7) * 8;   // swizzled k-offset
            #pragma unroll
            for (int i = 0; i < 4; ++i)
                af[ks][i] = *(const bf16x8*)&As[(wr * 64 + i * 16 + lr) * 64 + slot];
            #pragma unroll
            for (int j = 0; j < 4; ++j)
                bfv[ks][j] = *(const bf16x8*)&Bs[(wc * 64 + j * 16 + lr) * 64 + slot];
        }
        #pragma unroll
        for (int ks = 0; ks < 2; ++ks)
            #pragma unroll
            for (int i = 0; i < 4; ++i)
                #pragma unroll
                for (int j = 0; j < 4; ++j)
                    acc[i][j] = __builtin_amdgcn_mfma_f32_16x16x32_bf16(
                        af[ks][i], bfv[ks][j], acc[i][j], 0, 0, 0);
        __syncthreads();
    }

    // epilogue: C/D layout col=lane&15, row=(lane>>4)*4+reg
    #pragma unroll
    for (int j = 0; j < 4; ++j) {
        const int col = ncol0 + wc * 64 + j * 16 + lr;
        const float bz = bias[col];
        #pragma unroll
        for (int i = 0; i < 4; ++i) {
            const int rb = m0 + wr * 64 + i * 16 + lkq * 4;
            #pragma unroll
            for (int r = 0; r < 4; ++r) {
                const int row = rb + r;
                float v = acc[i][j][r] + bz;
                if (mode == 0)      v = __expf(fminf(fmaxf(v, -60.f), 30.f));
                else if (mode == 2) v = 1.f / (1.f + __expf(-v));
                else if (mode == 3) v *= gamma[row & (T_CTX - 1)];
                if (mode == 1 || mode == 2)
                    ((unsigned short*)out)[(size_t)row * C_DIM + col] = f2bf(v);
                else
                    ((float*)out)[(size_t)row * C_DIM + col] = v;
            }
        }
    }
}

// ---------------------------------------------------------------------------
// Chunk-local cumsum of expk + kvT[b,h,c,u] = bf16(expk * v * alpha[h,u]).
// sumk holds CHUNK-LOCAL prefix sums; aux[b,q,n] = raw chunk totals
// (prefix-summed on the fly in the wkv epilogue).
// ---------------------------------------------------------------------------
__global__ __launch_bounds__(256)
void cumsum_chunk(const float* __restrict__ expk, const unsigned short* __restrict__ vbf,
                  const float* __restrict__ alpha,
                  float* __restrict__ sumk, unsigned short* __restrict__ kvT,
                  float* __restrict__ aux)
{
    const int n = blockIdx.x * 256 + threadIdx.x;
    const int q = blockIdx.y;
    const int b = blockIdx.z;
    const int h = n >> 6, c = n & 63;
    const size_t base = ((size_t)b * T_CTX + q * 128) * C_DIM + n;
    unsigned short* kvrow = kvT + (((size_t)b * H_NUM + h) * HS + c) * T_CTX + q * 128;
    float s = 0.f;
    u16x8 buf;
    for (int i = 0; i < 128; ++i) {
        const size_t idx = base + (size_t)i * C_DIM;
        const float e  = expk[idx];
        const float vv = bf2f(vbf[idx]);
        const float a  = alpha[h * T_CTX + q * 128 + i];
        s += e;
        sumk[idx] = s;
        buf[i & 7] = f2bf(e * vv * a);
        if ((i & 7) == 7) *(u16x8*)(kvrow + i - 7) = buf;
    }
    aux[((size_t)b * 8 + q) * C_DIM + n] = s;
}

// ---------------------------------------------------------------------------
// wkv via MFMA (Toeplitz):  wkv[t,c] = sum_u twx[1023-t+u] * kvT[c,u]
// A-frags from 8 shift-replicas of twx in LDS; B = kvT tile in padded LDS.
// Epilogue: rwkv = sigr * beta[t] * acc / (sumk_chunk + prefix(aux))  (bf16)
// Each block's 128-t range lies in exactly one 128-chunk (q = blockIdx.x),
// so the aux prefix is summed once per thread (<=7 loads per channel).
// ---------------------------------------------------------------------------
#define REPL_STRIDE 1176
#define REPL_USED   1168

__global__ __launch_bounds__(256)
void wkv_mfma(const unsigned short* __restrict__ kvT,
              const float* __restrict__ sumk,
              const unsigned short* __restrict__ sigr,
              const float* __restrict__ tw, const float* __restrict__ beta,
              const float* __restrict__ aux,
              unsigned short* __restrict__ rwkv)
{
    __shared__ unsigned short repl[8 * REPL_STRIDE];
    __shared__ unsigned short kv_s[64 * 72];
    __shared__ unsigned short tw_s[1024];

    const int tid = threadIdx.x;
    const int bx = blockIdx.x;
    const int t0 = bx * 128;
    const int h  = blockIdx.y;
    const int b  = blockIdx.z;

    {
        const int i = tid * 4;
        const float4 v = *(const float4*)(tw + h * T_CTX + i);
        ushort4 o;
        o.x = f2bf(v.x); o.y = f2bf(v.y); o.z = f2bf(v.z); o.w = f2bf(v.w);
        *(ushort4*)&tw_s[i] = o;
    }
    __syncthreads();

    #pragma unroll
    for (int r = 0; r < 8; ++r)
        for (int i = tid; i < REPL_USED; i += 256) {
            const int src = i + r;
            repl[r * REPL_STRIDE + i] = (src < 1024) ? tw_s[src] : (unsigned short)0;
        }
    __syncthreads();

    const int w = tid >> 6, l = tid & 63;
    const int wr = w >> 1, wc = w & 1;
    const int lr = l & 15, lkq = l >> 4;

    const int r    = (7 - lr) & 7;
    const int S0   = 1023 - t0 - wr * 64 - lr + lkq * 8;
    const int abase = 2 * S0 + (2 * REPL_STRIDE - 2) * r;
    const char* repl_c = (const char*)repl;

    const int srow = tid >> 2;
    const int ucol = (tid & 3) * 16;
    const unsigned short* gkv = kvT + (((size_t)b * H_NUM + h) * HS + srow) * T_CTX + ucol;
    unsigned short* skv = &kv_s[srow * 72 + ucol];

    f32x4 acc[4][2];
    #pragma unroll
    for (int i = 0; i < 4; ++i) {
        acc[i][0] = (f32x4){0.f, 0.f, 0.f, 0.f};
        acc[i][1] = (f32x4){0.f, 0.f, 0.f, 0.f};
    }

    const int nsteps = t0 / 64 + 2;
    for (int ks = 0; ks < nsteps; ++ks) {
        const int u0 = ks * 64;
        const u16x8 q0 = *(const u16x8*)(gkv + u0);
        const u16x8 q1 = *(const u16x8*)(gkv + u0 + 8);
        __syncthreads();
        *(u16x8*)skv       = q0;
        *(u16x8*)(skv + 8) = q1;
        __syncthreads();

        const int ub = abase + 2 * u0;
        #pragma unroll
        for (int kk = 0; kk < 2; ++kk) {
            bf16x8 af[4], bfv[2];
            #pragma unroll
            for (int i = 0; i < 4; ++i)
                af[i] = *(const bf16x8*)(repl_c + (ub + kk * 64 - i * 32));
            #pragma unroll
            for (int j = 0; j < 2; ++j)
                bfv[j] = *(const bf16x8*)&kv_s[(wc * 32 + j * 16 + lr) * 72 + kk * 32 + lkq * 8];
            #pragma unroll
            for (int i = 0; i < 4; ++i)
                #pragma unroll
                for (int j = 0; j < 2; ++j)
                    acc[i][j] = __builtin_amdgcn_mfma_f32_16x16x32_bf16(
                        af[i], bfv[j], acc[i][j], 0, 0, 0);
        }
    }

    // aux prefix for this block's chunk (q' < bx), per channel
    float off[2];
    #pragma unroll
    for (int j = 0; j < 2; ++j) {
        const int cl = wc * 32 + j * 16 + lr;
        float o = 0.f;
        for (int q = 0; q < bx; ++q)
            o += aux[((size_t)b * 8 + q) * C_DIM + h * HS + cl];
        off[j] = o;
    }

    #pragma unroll
    for (int i = 0; i < 4; ++i) {
        const int tb = t0 + wr * 64 + i * 16 + lkq * 4;
        #pragma unroll
        for (int rg = 0; rg < 4; ++rg) {
            const int t = tb + rg;
            const float bet = beta[h * T_CTX + t];
            const size_t row_off = ((size_t)(b * T_CTX + t)) * C_DIM + h * HS;
            #pragma unroll
            for (int j = 0; j < 2; ++j) {
                const int cl = wc * 32 + j * 16 + lr;
                const float sk = sumk[row_off + cl] + off[j];
                const float sr = bf2f(sigr[row_off + cl]);
                rwkv[row_off + cl] = f2bf(sr * bet * acc[i][j][rg] / sk);
            }
        }
    }
}

// ---------------------------------------------------------------------------
extern "C" void kernel_launch(void* const* d_in, const int* in_sizes, int n_in,
                              void* d_out, int out_size, void* d_ws, size_t ws_size,
                              hipStream_t stream)
{
    const float* x     = (const float*)d_in[0];
    const float* tw    = (const float*)d_in[1];
    const float* alpha = (const float*)d_in[2];
    const float* beta  = (const float*)d_in[3];
    const float* gamma = (const float*)d_in[4];
    const float* Wk    = (const float*)d_in[5];
    const float* bk    = (const float*)d_in[6];
    const float* Wv    = (const float*)d_in[7];
    const float* bv    = (const float*)d_in[8];
    const float* Wr    = (const float*)d_in[9];
    const float* br    = (const float*)d_in[10];
    const float* Wo    = (const float*)d_in[11];
    const float* bo    = (const float*)d_in[12];
    float* out = (float*)d_out;

    // workspace layout (bytes), max 128M:
    //  [0,32M)   expk fp32    -> rwkv bf16 [0,16M) after cumsum
    //  [32,48M)  v bf16
    //  [48,56M)  weights bf16 (Wk,Wv,Wr,Wo stacked @ 2MB each)
    //  [56,56.25M) aux (raw chunk totals)
    //  [64,96M)  sumk fp32 (chunk-local)  (xs bf16 overlays [64,80M) during proj)
    //  [96,112M) sigr bf16
    //  [112,128M) kvT bf16
    char* W = (char*)d_ws;
    float* expk          = (float*)W;
    unsigned short* rwkv = (unsigned short*)W;
    unsigned short* vbf  = (unsigned short*)(W + (32ull << 20));
    unsigned short* wbf  = (unsigned short*)(W + (48ull << 20));
    float* aux           = (float*)(W + (56ull << 20));
    float* sumk          = (float*)(W + (64ull << 20));
    unsigned short* xs   = (unsigned short*)(W + (64ull << 20));
    unsigned short* sigr = (unsigned short*)(W + (96ull << 20));
    unsigned short* kvT  = (unsigned short*)(W + (112ull << 20));

    const size_t WSZ = (size_t)C_DIM * C_DIM;

    convert_all<<<dim3(12288), 256, 0, stream>>>(x, xs, Wk, Wv, Wr, Wo, wbf);

    // k,v,r projections as one N=3072 GEMM (W stacked), XCD-swizzled
    mfma_gemm64<<<dim3(1536), 256, 0, stream>>>(
        xs, wbf, bk, bv, br, expk, vbf, sigr, gamma, 1);

    cumsum_chunk<<<dim3(4, 8, 8), 256, 0, stream>>>(expk, vbf, alpha, sumk, kvT, aux);

    wkv_mfma<<<dim3(8, 16, 8), 256, 0, stream>>>(
        kvT, sumk, sigr, tw, beta, aux, rwkv);

    // output projection + gamma
    mfma_gemm64<<<dim3(512), 256, 0, stream>>>(
        rwkv, wbf + 3 * WSZ, bo, nullptr, nullptr,
        out, nullptr, nullptr, gamma, 0);
}